// Round 4
// baseline (2022.685 us; speedup 1.0000x reference)
//
#include <hip/hip_runtime.h>

#define TT 2048
#define BQ 512
#define LAYERS 10
#define NC 7
#define CH 8               // timesteps per chunk (per barrier interval)
#define NCH (TT / CH)      // 256 chunks

// LDS layout strides (in dwords). Elem slot padded 13->20 so the FC
// chunk-read (stride C_S=40 dwords) lands on banks {0,8,16,24} -> 2-way
// (free) instead of the 8-way conflict of stride 32. All strides are
// 16B multiples so uint4 reads stay aligned.
#define E_S 20
#define C_S (2 * E_S)              // 40
#define S_S (CH * C_S)             // 320
#define P_S ((LAYERS + 1) * S_S)   // 3520

typedef _Float16 half2v __attribute__((ext_vector_type(2)));

__device__ __forceinline__ float sigm(float z) {
  return __builtin_amdgcn_rcpf(1.0f + __expf(-z));
}
// f32 += dot(f16x2, f16x2) -- v_dot2_f32_f16
__device__ __forceinline__ float dot2(unsigned w, unsigned v, float acc) {
  return __builtin_amdgcn_fdot2(__builtin_bit_cast(half2v, w),
                                __builtin_bit_cast(half2v, v), acc, false);
}
// RNE pack of two floats into f16x2 dword
__device__ __forceinline__ unsigned pkh2(float a, float b) {
  union { _Float16 h[2]; unsigned u; } z;
  z.h[0] = (_Float16)a; z.h[1] = (_Float16)b;
  return z.u;
}

#define LOAD13(dst, src)                         \
  do {                                           \
    *(uint4*)&(dst)[0] = *(const uint4*)((src) + 0); \
    *(uint4*)&(dst)[4] = *(const uint4*)((src) + 4); \
    *(uint4*)&(dst)[8] = *(const uint4*)((src) + 8); \
    (dst)[12] = (src)[12];                       \
  } while (0)

// R12: x-phase / h-phase split + staging moved to FC waves.
// R11 post-mortem: VALUBusy 71%, VGPR only 84 -> compiler kept the j-loop
// in program order; each cell's serial chain (Ov read -> 52 h-dots ->
// act -> publish -> readback) is exposed, while the INDEPENDENT x-side
// work (52 dots/cell, no cross-cell dep) sits serialized between them.
// Fix: per step, phase A computes x-partials for 4 cells into 16 f32
// accumulators (208 independent dot2, pure ILP), phase B runs the 4
// serial h-recurrences with a rolling 13-reg Ov buffer. A1,B1,A2,B2.
// Also: x staging moved off wave 0 (layer-critical) onto the nearly-idle
// FC waves (wave 10 stages elem 0, wave 11 elem 1; 26 lanes each).
// Per-row arithmetic bit-identical to R11 (x-acc starts from bias, same
// dot order; h-chain from 0; summed at activation).
__launch_bounds__(768, 3)
__global__ void lstm_fused(const float* __restrict__ x,
                           const float* __restrict__ h0,
                           const float* __restrict__ c0,
                           const float* __restrict__ Wih,
                           const float* __restrict__ Whh,
                           const float* __restrict__ bias,
                           const float* __restrict__ fcw,
                           const float* __restrict__ fcb,
                           float* __restrict__ out) {
  __shared__ __align__(16) unsigned hs[2 * P_S];
  __shared__ float eb[2][CH][8];   // FC softmax exp staging

  const int tid = threadIdx.x;
  const int w = tid >> 6;          // 0..9 layers, 10/11 = FC elem 0/1
  const int lane = tid & 63;
  const int b0 = blockIdx.x * 2;   // first batch elem of this block
  const int e = lane & 1;          // element
  const int u = lane >> 1;         // unit 0..24
  const bool on = (w < LAYERS) && (lane < 50);
  const bool isfc = (w >= LAYERS) && (lane < 7 * CH);
  const int efc = w - LAYERS;              // FC: which elem (0/1)
  const int jg = lane / 7;                 // FC: cell within chunk
  const int cls = lane - jg * 7;           // FC: class

  // Weights: Wx/Wh[r][k] = f16-pair k of gate-row r (i,f,g,o) for unit u.
  // FC waves reuse Wx[0][*] and bb[0] for fc weights/bias.
  unsigned Wx[4][13], Wh[4][13];
  float bb[4] = {0.f, 0.f, 0.f, 0.f};
  float c = 0.f;

  // FC-wave x staging roles: wave 10 -> elem 0, wave 11 -> elem 1.
  // 26 lanes = 2 groups of 13 (cells sgg*4 .. sgg*4+3).
  const int sgg = lane / 13;               // group 0..1 (lane<26)
  const int li = lane - sgg * 13;          // dword 0..12
  const int jb = sgg * 4;                  // first cell of this group
  const int i0 = 2 * li;
  const int i1 = (li < 12) ? (2 * li + 1) : 0;   // clamped in-bounds
  const bool stg = (w >= LAYERS) && (lane < 26);
  float xA[4], xB[4];
#pragma unroll
  for (int jj = 0; jj < 4; ++jj) { xA[jj] = 0.f; xB[jj] = 0.f; }

  if (on) {
#pragma unroll
    for (int r = 0; r < 4; ++r) {
      const int row = u + 25 * r;          // torch order: i,f,g,o
      const float* px = Wih + (w * 100 + row) * 25;
      const float* ph = Whh + (w * 100 + row) * 25;
#pragma unroll
      for (int k = 0; k < 13; ++k) {
        const int k0 = 2 * k, k1 = 2 * k + 1;
        Wx[r][k] = pkh2(px[k0], (k1 < 25) ? px[k1] : 0.f);
        Wh[r][k] = pkh2(ph[k0], (k1 < 25) ? ph[k1] : 0.f);
      }
      bb[r] = bias[w * 100 + row];
    }
    c = c0[(w * BQ + b0 + e) * 25 + u];
  } else if (isfc) {
    const float* pf = fcw + cls * 25;
#pragma unroll
    for (int k = 0; k < 13; ++k) {
      const int k0 = 2 * k, k1 = 2 * k + 1;
      Wx[0][k] = pkh2(pf[k0], (k1 < 25) ? pf[k1] : 0.f);
    }
    bb[0] = fcb[cls];
  }

  // h0 -> packed pairs at [prev-parity of first active step][w+1][CH-1][e].
  {
    float h00 = 0.f;
    if (on) h00 = h0[(w * BQ + b0 + e) * 25 + u];
    const float hn = __shfl_xor(h00, 2);   // same-elem neighbor unit u^1
    if (on && (lane & 2) == 0) {           // even-u owners publish pairs
      hs[((w & 1) ^ 1) * P_S + (w + 1) * S_S + (CH - 1) * C_S + e * E_S +
         (u >> 1)] = pkh2(h00, (u == 24) ? 0.f : hn);
    }
  }

  if (stg) {
    // chunk 0 -> parity 1 (read at m=0)
#pragma unroll
    for (int jj = 0; jj < 4; ++jj) {
      const float* p = x + ((size_t)(jb + jj) * BQ + (b0 + efc)) * 25;
      hs[1 * P_S + (jb + jj) * C_S + efc * E_S + li] =
          pkh2(p[i0], (li < 12) ? p[i1] : 0.f);
    }
    // preload chunk 1 into regs (staged to LDS at m=0)
#pragma unroll
    for (int jj = 0; jj < 4; ++jj) {
      const float* p = x + ((size_t)(CH + jb + jj) * BQ + (b0 + efc)) * 25;
      xA[jj] = p[i0];
      xB[jj] = (li < 12) ? p[i1] : 0.f;
    }
  }
  __syncthreads();

  for (int m = 0; m < NCH + LAYERS; ++m) {
    const int pr = (m & 1) ^ 1;                // read parity
    const int pw = m & 1;                      // write parity

    if (w < LAYERS) {
      const int mc = m - w;                    // chunk index (wave-uniform)
      if ((unsigned)mc < (unsigned)NCH && lane < 50) {
        const unsigned* ibase = hs + pr * P_S + w * S_S + e * E_S;
        const unsigned* o0p =
            hs + pr * P_S + (w + 1) * S_S + (CH - 1) * C_S + e * E_S;
        unsigned* obase = hs + pw * P_S + (w + 1) * S_S + e * E_S;

        unsigned Ovp[13];            // rolling own-h of previous cell
        LOAD13(Ovp, o0p);

#pragma unroll
        for (int half = 0; half < 2; ++half) {
          const int j0 = half * 4;
          // ---- Phase A: x-side partials for cells j0..j0+3 (independent)
          float xg[4][4];            // [cell][gate] = bias + Wx . input
#pragma unroll
          for (int jj = 0; jj < 4; ++jj) {
            unsigned Iv[13];
            LOAD13(Iv, ibase + (j0 + jj) * C_S);
            float ai = bb[0], af = bb[1], ag = bb[2], ao = bb[3];
#pragma unroll
            for (int k = 0; k < 13; ++k) {
              ai = dot2(Wx[0][k], Iv[k], ai);
              af = dot2(Wx[1][k], Iv[k], af);
              ag = dot2(Wx[2][k], Iv[k], ag);
              ao = dot2(Wx[3][k], Iv[k], ao);
            }
            xg[jj][0] = ai; xg[jj][1] = af; xg[jj][2] = ag; xg[jj][3] = ao;
          }
          // ---- Phase B: serial h-recurrence for cells j0..j0+3
#pragma unroll
          for (int jj = 0; jj < 4; ++jj) {
            const int j = j0 + jj;
            float hi = 0.f, hf = 0.f, hg = 0.f, ho = 0.f;
#pragma unroll
            for (int k = 0; k < 13; ++k) {
              hi = dot2(Wh[0][k], Ovp[k], hi);
              hf = dot2(Wh[1][k], Ovp[k], hf);
              hg = dot2(Wh[2][k], Ovp[k], hg);
              ho = dot2(Wh[3][k], Ovp[k], ho);
            }
            const float gi = sigm(xg[jj][0] + hi);
            const float gf = sigm(xg[jj][1] + hf);
            const float pg = xg[jj][2] + hg;
            const float gg = 2.0f * sigm(2.0f * pg) - 1.0f;  // tanh
            const float go = sigm(xg[jj][3] + ho);
            c = gf * c + gi * gg;
            const float th = 2.0f * sigm(2.0f * c) - 1.0f;   // tanh(c)
            const float hv = go * th;
            const float hn = __shfl_xor(hv, 2);  // same-elem neighbor unit
            if ((lane & 2) == 0) {               // even-u owners publish
              obase[j * C_S + (u >> 1)] = pkh2(hv, (u == 24) ? 0.f : hn);
            }
            if (j < CH - 1) {
              LOAD13(Ovp, obase + j * C_S);      // readback for next cell
            }
          }
        }
      }
    } else {
      // FC waves: x staging for chunk m+1 / prefetch m+2 (stg lanes) ...
      if (stg) {
        if (m + 1 < NCH) {
#pragma unroll
          for (int jj = 0; jj < 4; ++jj) {
            hs[pw * P_S + (jb + jj) * C_S + efc * E_S + li] =
                pkh2(xA[jj], xB[jj]);
          }
        }
        if (m + 2 < NCH) {
          const size_t tb = (size_t)(m + 2) * CH + jb;
#pragma unroll
          for (int jj = 0; jj < 4; ++jj) {
            const float* p = x + ((tb + jj) * BQ + (b0 + efc)) * 25;
            xA[jj] = p[i0];
            xB[jj] = (li < 12) ? p[i1] : 0.f;
          }
        }
      }
      // ... and FC + softmax for elem efc: chunk mc = m-10 (parity pr)
      const int mc = m - LAYERS;
      if (isfc && (unsigned)mc < (unsigned)NCH) {
        const unsigned* hp =
            hs + pr * P_S + LAYERS * S_S + jg * C_S + efc * E_S;
        unsigned Hv[13];
        LOAD13(Hv, hp);
        float acc = bb[0];
#pragma unroll
        for (int k = 0; k < 13; ++k) acc = dot2(Wx[0][k], Hv[k], acc);
        const float ev = __expf(acc);           // logits small; no max-sub
        eb[efc][jg][cls] = ev;                  // same-wave LDS, ordered
        const float ssum = eb[efc][jg][0] + eb[efc][jg][1] + eb[efc][jg][2] +
                           eb[efc][jg][3] + eb[efc][jg][4] + eb[efc][jg][5] +
                           eb[efc][jg][6];
        const int t = mc * CH + jg;
        out[((size_t)t * BQ + (b0 + efc)) * NC + cls] =
            ev * __builtin_amdgcn_rcpf(ssum);
      }
    }
    __syncthreads();   // ONE barrier per chunk-step (266 total)
  }
}

extern "C" void kernel_launch(void* const* d_in, const int* in_sizes, int n_in,
                              void* d_out, int out_size, void* d_ws, size_t ws_size,
                              hipStream_t stream) {
  const float* x   = (const float*)d_in[0];
  const float* h0  = (const float*)d_in[1];
  const float* c0  = (const float*)d_in[2];
  const float* Wih = (const float*)d_in[3];
  const float* Whh = (const float*)d_in[4];
  const float* b   = (const float*)d_in[5];
  const float* fcw = (const float*)d_in[6];
  const float* fcb = (const float*)d_in[7];
  float* out = (float*)d_out;

  lstm_fused<<<dim3(256), dim3(768), 0, stream>>>(x, h0, c0, Wih, Whh, b, fcw,
                                                  fcb, out);
}

// Round 5
// 1378.292 us; speedup vs baseline: 1.4675x; 1.4675x over previous
//
#include <hip/hip_runtime.h>

#define TT 2048
#define BQ 512
#define LAYERS 10
#define NC 7
#define CH 8               // timesteps per chunk (per barrier interval)
#define NCH (TT / CH)      // 256 chunks

// LDS slot strides (dwords). Slot = [elem0: 16dw][elem1: 16dw] of f16
// pairs (z[2k],z[2k+1]); dwords 13-15 and all pad halves are ZERO
// (one-time memset) so MFMA A-frags can read k=0..31 directly.
#define E_S 16
#define C_S (2 * E_S)              // 32
#define S_S (CH * C_S)             // 256
#define P_S ((LAYERS + 1) * S_S)   // 2816
#define GPW 224                    // gate scratch floats per layer wave

typedef _Float16 half2v __attribute__((ext_vector_type(2)));
typedef _Float16 f16x8 __attribute__((ext_vector_type(8)));
typedef float f32x4 __attribute__((ext_vector_type(4)));

__device__ __forceinline__ float sigm(float z) {
  return __builtin_amdgcn_rcpf(1.0f + __expf(-z));
}
// f32 += dot(f16x2, f16x2) -- v_dot2_f32_f16 (FC wave only now)
__device__ __forceinline__ float dot2(unsigned w, unsigned v, float acc) {
  return __builtin_amdgcn_fdot2(__builtin_bit_cast(half2v, w),
                                __builtin_bit_cast(half2v, v), acc, false);
}
// RNE pack of two floats into f16x2 dword
__device__ __forceinline__ unsigned pkh2(float a, float b) {
  union { _Float16 h[2]; unsigned u; } z;
  z.h[0] = (_Float16)a; z.h[1] = (_Float16)b;
  return z.u;
}

#define LOAD13(dst, src)                             \
  do {                                               \
    *(uint4*)&(dst)[0] = *(const uint4*)((src) + 0); \
    *(uint4*)&(dst)[4] = *(const uint4*)((src) + 4); \
    *(uint4*)&(dst)[8] = *(const uint4*)((src) + 8); \
    (dst)[12] = (src)[12];                           \
  } while (0)

// R13: MFMA gate computation. R12 post-mortem: VALUBusy 71% IS the dot2
// issue work (104 dot2 x ~4cy/cell); floor of dot2 structure ~1450us.
// Replace with v_mfma_f32_16x16x32_f16 in swapped orientation:
//   C[E=2 rows][G gates] = A(z: elems as M) x B(W^T: gates as N)
//   7 N-tiles (112>=100 gates) x 2 K-steps (x-part, h-part) = 14 MFMA/cell.
// k-layout risk eliminated by symmetry: HW pairs A-slot(q,j) with
// B-slot(q,j), so packing BOTH sides as k=8q+j (= the f16-pair LDS
// format) is correct for any true k-mapping. C/D layout is the HW-
// verified col=lane&15, row=4*(lane>>4)+reg -> elems = regs 0/1 of
// lanes 0-15. Scatter 14 f32/lane to gp[] (pos=(G%25)*4+G/25), then the
// (u,e)-lane activation code (UNCHANGED from R11) reads {i,f,g,o} as one
// b128. Bias added post-MFMA (order change only; error stays dominated
// by f16 input quantization). FC/staging waves unchanged.
__launch_bounds__(768, 3)
__global__ void lstm_fused(const float* __restrict__ x,
                           const float* __restrict__ h0,
                           const float* __restrict__ c0,
                           const float* __restrict__ Wih,
                           const float* __restrict__ Whh,
                           const float* __restrict__ bias,
                           const float* __restrict__ fcw,
                           const float* __restrict__ fcb,
                           float* __restrict__ out) {
  __shared__ __align__(16) unsigned hs[2 * P_S];
  __shared__ __align__(16) float gp[LAYERS][GPW];  // gate scratch per wave
  __shared__ float eb[2][CH][8];   // FC softmax exp staging

  const int tid = threadIdx.x;
  const int w = tid >> 6;          // 0..9 layers, 10/11 = FC+stage elem 0/1
  const int lane = tid & 63;
  const int b0 = blockIdx.x * 2;   // first batch elem of this block
  const int e = lane & 1;          // activation role: element
  const int u = lane >> 1;         // activation role: unit 0..24
  const int n15 = lane & 15;       // MFMA roles
  const int q4 = lane >> 4;
  const int arb = (n15 & 1) * E_S + 4 * q4;  // A-frag dword offset in slot
  const bool lay = (w < LAYERS);
  const bool act = lay && (lane < 50);
  const bool isfc = (w >= LAYERS) && (lane < 7 * CH);
  const int efc = w - LAYERS;              // FC: which elem (0/1)
  const int jg = lane / 7;                 // FC: cell within chunk
  const int cls = lane - jg * 7;           // FC: class

  f16x8 BX[7], BH[7];              // B-frags: Wih / Whh, k=8*q4+j packing
  int ga[7];                       // gate scatter addrs (lanes 0..15)
  unsigned Wf[13];                 // FC weights (f16 pairs)
  float bb[4] = {0.f, 0.f, 0.f, 0.f};
  float bf = 0.f;
  float c = 0.f;

  // FC-wave x staging roles: wave 10 -> elem 0, wave 11 -> elem 1.
  const int sgg = lane / 13;               // group 0..1 (lane<26)
  const int li = lane - sgg * 13;          // dword 0..12
  const int jb = sgg * 4;                  // first cell of this group
  const int i0 = 2 * li;
  const int i1 = (li < 12) ? (2 * li + 1) : 0;   // clamped in-bounds
  const bool stg = (w >= LAYERS) && (lane < 26);
  float xA[4], xB[4];
#pragma unroll
  for (int jj = 0; jj < 4; ++jj) { xA[jj] = 0.f; xB[jj] = 0.f; }

  // one-time zero of hs (pad dwords must read as 0 forever)
  for (int i = tid; i < 2 * P_S; i += 768) hs[i] = 0u;

  if (lay) {
#pragma unroll
    for (int nt = 0; nt < 7; ++nt) {
      const int G = 16 * nt + n15;         // gate row this lane's B-col
      const bool gok = (G < 100);
      const float* px = Wih + (w * 100 + (gok ? G : 0)) * 25;
      const float* ph = Whh + (w * 100 + (gok ? G : 0)) * 25;
#pragma unroll
      for (int d = 0; d < 4; ++d) {
        const int k0 = 8 * q4 + 2 * d, k1 = k0 + 1;
        float x0 = 0.f, x1 = 0.f, h0v = 0.f, h1v = 0.f;
        if (gok && k0 < 25) { x0 = px[k0]; h0v = ph[k0]; }
        if (gok && k1 < 25) { x1 = px[k1]; h1v = ph[k1]; }
        BX[nt][2 * d]     = (_Float16)x0;
        BX[nt][2 * d + 1] = (_Float16)x1;
        BH[nt][2 * d]     = (_Float16)h0v;
        BH[nt][2 * d + 1] = (_Float16)h1v;
      }
      const int Gs = 16 * nt + lane;       // scatter addr (lanes 0..15)
      ga[nt] = (Gs % 25) * 4 + (Gs / 25);
    }
    if (lane < 50) {
#pragma unroll
      for (int r = 0; r < 4; ++r) bb[r] = bias[w * 100 + u + 25 * r];
      c = c0[(w * BQ + b0 + e) * 25 + u];
    }
  } else if (isfc) {
    const float* pf = fcw + cls * 25;
#pragma unroll
    for (int k = 0; k < 13; ++k) {
      const int k0 = 2 * k, k1 = 2 * k + 1;
      Wf[k] = pkh2(pf[k0], (k1 < 25) ? pf[k1] : 0.f);
    }
    bf = fcb[cls];
  }
  __syncthreads();   // zero-fill visible before pair staging

  // h0 -> packed pairs at [prev-parity of first active step][w+1][CH-1][e]
  {
    float h00 = 0.f;
    if (act) h00 = h0[(w * BQ + b0 + e) * 25 + u];
    const float hn = __shfl_xor(h00, 2);   // same-elem neighbor unit u^1
    if (act && (lane & 2) == 0) {          // even-u owners publish pairs
      hs[((w & 1) ^ 1) * P_S + (w + 1) * S_S + (CH - 1) * C_S + e * E_S +
         (u >> 1)] = pkh2(h00, (u == 24) ? 0.f : hn);
    }
  }

  if (stg) {
    // chunk 0 -> parity 1 (read at m=0)
#pragma unroll
    for (int jj = 0; jj < 4; ++jj) {
      const float* p = x + ((size_t)(jb + jj) * BQ + (b0 + efc)) * 25;
      hs[1 * P_S + (jb + jj) * C_S + efc * E_S + li] =
          pkh2(p[i0], (li < 12) ? p[i1] : 0.f);
    }
    // preload chunk 1 into regs (staged to LDS at m=0)
#pragma unroll
    for (int jj = 0; jj < 4; ++jj) {
      const float* p = x + ((size_t)(CH + jb + jj) * BQ + (b0 + efc)) * 25;
      xA[jj] = p[i0];
      xB[jj] = (li < 12) ? p[i1] : 0.f;
    }
  }
  __syncthreads();

  for (int m = 0; m < NCH + LAYERS; ++m) {
    const int pr = (m & 1) ^ 1;                // read parity
    const int pw = m & 1;                      // write parity

    if (lay) {
      const int mc = m - w;                    // chunk index (wave-uniform)
      if ((unsigned)mc < (unsigned)NCH) {
        const unsigned* ibase = hs + pr * P_S + w * S_S + arb;
        const unsigned* o0p =
            hs + pr * P_S + (w + 1) * S_S + (CH - 1) * C_S + arb;
        unsigned* ob = hs + pw * P_S + (w + 1) * S_S;  // publish base
        const unsigned* obr = ob + arb;                // A-read view of own h
        float* gw = &gp[w][0];

#pragma unroll
        for (int j = 0; j < CH; ++j) {
          // A-frags: one b128 each (k = 8*q4 + 0..7 of elem n15&1)
          const uint4 axu = *(const uint4*)(ibase + j * C_S);
          const uint4 ahu = (j == 0) ? *(const uint4*)o0p
                                     : *(const uint4*)(obr + (j - 1) * C_S);
          const f16x8 ax = __builtin_bit_cast(f16x8, axu);
          const f16x8 ah = __builtin_bit_cast(f16x8, ahu);
          f32x4 Cr[7];
#pragma unroll
          for (int nt = 0; nt < 7; ++nt) {
            f32x4 z4 = {0.f, 0.f, 0.f, 0.f};
            z4 = __builtin_amdgcn_mfma_f32_16x16x32_f16(ax, BX[nt], z4,
                                                        0, 0, 0);
            Cr[nt] = __builtin_amdgcn_mfma_f32_16x16x32_f16(ah, BH[nt], z4,
                                                            0, 0, 0);
          }
          // scatter gates: reg0 = elem0 (C row0), reg1 = elem1 (C row1)
          if (lane < 16) {
#pragma unroll
            for (int nt = 0; nt < 7; ++nt) {
              if (16 * nt + lane < 100) {
                gw[ga[nt]]       = Cr[nt][0];
                gw[ga[nt] + 112] = Cr[nt][1];
              }
            }
          }
          // activations (unchanged math from R11; bias added here)
          if (lane < 50) {
            const f32x4 gv = *(const f32x4*)(gw + u * 4 + e * 112);
            const float gi = sigm(gv[0] + bb[0]);
            const float gf = sigm(gv[1] + bb[1]);
            const float pg = gv[2] + bb[2];
            const float gg = 2.0f * sigm(2.0f * pg) - 1.0f;  // tanh
            const float go = sigm(gv[3] + bb[3]);
            c = gf * c + gi * gg;
            const float th = 2.0f * sigm(2.0f * c) - 1.0f;   // tanh(c)
            const float hv = go * th;
            const float hn = __shfl_xor(hv, 2);  // same-elem neighbor unit
            if ((lane & 2) == 0) {               // even-u owners publish
              ob[j * C_S + e * E_S + (u >> 1)] =
                  pkh2(hv, (u == 24) ? 0.f : hn);
            }
          }
        }
      }
    } else {
      // FC waves: x staging for chunk m+1 / prefetch m+2 (stg lanes) ...
      if (stg) {
        if (m + 1 < NCH) {
#pragma unroll
          for (int jj = 0; jj < 4; ++jj) {
            hs[pw * P_S + (jb + jj) * C_S + efc * E_S + li] =
                pkh2(xA[jj], xB[jj]);
          }
        }
        if (m + 2 < NCH) {
          const size_t tb = (size_t)(m + 2) * CH + jb;
#pragma unroll
          for (int jj = 0; jj < 4; ++jj) {
            const float* p = x + ((tb + jj) * BQ + (b0 + efc)) * 25;
            xA[jj] = p[i0];
            xB[jj] = (li < 12) ? p[i1] : 0.f;
          }
        }
      }
      // ... and FC + softmax for elem efc: chunk mc = m-10 (parity pr)
      const int mc = m - LAYERS;
      if (isfc && (unsigned)mc < (unsigned)NCH) {
        const unsigned* hp =
            hs + pr * P_S + LAYERS * S_S + jg * C_S + efc * E_S;
        unsigned Hv[13];
        LOAD13(Hv, hp);
        float acc = bf;
#pragma unroll
        for (int k = 0; k < 13; ++k) acc = dot2(Wf[k], Hv[k], acc);
        const float ev = __expf(acc);           // logits small; no max-sub
        eb[efc][jg][cls] = ev;                  // same-wave LDS, ordered
        const float ssum = eb[efc][jg][0] + eb[efc][jg][1] + eb[efc][jg][2] +
                           eb[efc][jg][3] + eb[efc][jg][4] + eb[efc][jg][5] +
                           eb[efc][jg][6];
        const int t = mc * CH + jg;
        out[((size_t)t * BQ + (b0 + efc)) * NC + cls] =
            ev * __builtin_amdgcn_rcpf(ssum);
      }
    }
    __syncthreads();   // ONE barrier per chunk-step (266 total)
  }
}

extern "C" void kernel_launch(void* const* d_in, const int* in_sizes, int n_in,
                              void* d_out, int out_size, void* d_ws, size_t ws_size,
                              hipStream_t stream) {
  const float* x   = (const float*)d_in[0];
  const float* h0  = (const float*)d_in[1];
  const float* c0  = (const float*)d_in[2];
  const float* Wih = (const float*)d_in[3];
  const float* Whh = (const float*)d_in[4];
  const float* b   = (const float*)d_in[5];
  const float* fcw = (const float*)d_in[6];
  const float* fcb = (const float*)d_in[7];
  float* out = (float*)d_out;

  lstm_fused<<<dim3(256), dim3(768), 0, stream>>>(x, h0, c0, Wih, Whh, b, fcw,
                                                  fcb, out);
}